// Round 6
// baseline (735.438 us; speedup 1.0000x reference)
//
#include <hip/hip_runtime.h>
#include <math.h>

#define NN 2048
#define NM1 2047
#define EDGES (NN * NM1)      // 4,192,256
#define KORD 8
#define NHEADS 4
#define BETA 0.5f
#define EPSV 1e-6f

typedef __attribute__((ext_vector_type(8))) short bf16x8;
typedef __attribute__((ext_vector_type(4))) float f32x4;

__device__ __forceinline__ unsigned short f2bf(float f) {
    unsigned u = __builtin_bit_cast(unsigned, f);
    u += 0x7FFF + ((u >> 16) & 1);          // round-to-nearest-even
    return (unsigned short)(u >> 16);
}
__device__ __forceinline__ float bf2f(unsigned short h) {
    unsigned u = ((unsigned)h) << 16;
    return __builtin_bit_cast(float, u);
}

#define GLD16(gp, lp) __builtin_amdgcn_global_load_lds(                         \
    (const __attribute__((address_space(1))) void*)(gp),                        \
    (__attribute__((address_space(3))) void*)(lp), 16, 0, 0)

// ---------------- kernel 1: edge softmax ----------------
__global__ void k_prob(const float* __restrict__ logits, float* __restrict__ out) {
    int e = blockIdx.x * 256 + threadIdx.x;
    if (e >= EDGES) return;
    float l0 = logits[e];
    float l1 = logits[EDGES + e];
    float p0 = 1.f / (1.f + __expf(BETA * (l1 - l0)));
    float p1 = 1.f / (1.f + __expf(BETA * (l0 - l1)));
    out[e]         = p0;
    out[EDGES + e] = p1;
}

// ---------------- kernel 2: row sums -> dinv = 1/sqrt(sum+eps) ----------------
__global__ __launch_bounds__(256) void k_dinv(const float* __restrict__ out, float* __restrict__ dinv) {
    int row = blockIdx.x, br = blockIdx.y;
    const float* p = out + (size_t)br * EDGES + (size_t)row * NM1;
    float s = 0.f;
    for (int t = threadIdx.x; t < NM1; t += 256) s += p[t];
    for (int off = 32; off; off >>= 1) s += __shfl_down(s, off);
    __shared__ float red[4];
    if ((threadIdx.x & 63) == 0) red[threadIdx.x >> 6] = s;
    __syncthreads();
    if (threadIdx.x == 0)
        dinv[br * NN + row] = 1.f / sqrtf(red[0] + red[1] + red[2] + red[3] + EPSV);
}

// ---------------- kernel 3: Lb = bf16(-dinv_i * p * dinv_j), diag 0 ----------------
__global__ __launch_bounds__(256) void k_build(const float* __restrict__ out, const float* __restrict__ dinv,
                                               unsigned short* __restrict__ Lb0, unsigned short* __restrict__ Lb1) {
    int idx = blockIdx.x * 256 + threadIdx.x;   // over N*N
    int br = blockIdx.y;
    int i = idx >> 11, j = idx & (NN - 1);
    unsigned short* Lb = br ? Lb1 : Lb0;
    float v = 0.f;
    if (i != j) {
        float pp = out[(size_t)br * EDGES + (size_t)i * NM1 + (j < i ? j : j - 1)];
        v = -dinv[br * NN + i] * pp * dinv[br * NN + j];
    }
    Lb[idx] = f2bf(v);
}

// ---------------- kernel 4: 64x64 bf16 transpose (dual-branch) ----------------
__global__ __launch_bounds__(256) void k_transpose(
    const unsigned short* __restrict__ S0, const unsigned short* __restrict__ S1,
    unsigned short* __restrict__ D0, unsigned short* __restrict__ D1) {
    __shared__ unsigned short T[64 * 66];
    const unsigned short* S = blockIdx.z ? S1 : S0;
    unsigned short* D = blockIdx.z ? D1 : D0;
    int t = threadIdx.x;
    int I0 = blockIdx.y * 64, J0 = blockIdx.x * 64;
    int r = t >> 2, cb = (t & 3) * 16;
    {
        const uint4* src = (const uint4*)(S + (size_t)(I0 + r) * NN + J0 + cb);
        uint4 v0 = src[0], v1 = src[1];
        unsigned* d = (unsigned*)&T[r * 66 + cb];
        d[0] = v0.x; d[1] = v0.y; d[2] = v0.z; d[3] = v0.w;
        d[4] = v1.x; d[5] = v1.y; d[6] = v1.z; d[7] = v1.w;
    }
    __syncthreads();
    union { unsigned short u[16]; uint4 q[2]; } pk;
#pragma unroll
    for (int q = 0; q < 16; ++q) pk.u[q] = T[(cb + q) * 66 + r];
    unsigned short* dst = D + (size_t)(J0 + r) * NN + I0 + cb;
    ((uint4*)dst)[0] = pk.q[0];
    ((uint4*)dst)[1] = pk.q[1];
}

// ---------------- kernel 5: dual-branch MFMA GEMM: Un = 2*(A @ BT^T) - Um2 ----------------
// A = U_{n-1} (row-major bf16), BT = Lb (= (L^T)^T = L), 128x128 tile, 4 waves,
// each wave 64x64 via 4x4 frags of 16x16x32. XOR chunk swizzle both sides (rule #21).
// v2: double-buffered LDS, T3 minimum-2-phase schedule (stage t+1 before compute t,
// ONE barrier per K-step; stage latency hides under ds_read+MFMA of current step).
__global__ __launch_bounds__(256) void k_cheb(
    const unsigned short* __restrict__ A0, const unsigned short* __restrict__ A1,
    const unsigned short* __restrict__ B0, const unsigned short* __restrict__ B1,
    const unsigned short* __restrict__ P0, const unsigned short* __restrict__ P1,
    unsigned short* __restrict__ O0, unsigned short* __restrict__ O1, int first) {
    __shared__ unsigned short As[2][128 * 32];   // linear [row][k], k-chunks XOR-swizzled
    __shared__ unsigned short Bs[2][128 * 32];
    const int z = blockIdx.z;
    const unsigned short* A   = z ? A1 : A0;
    const unsigned short* BT  = z ? B1 : B0;
    const unsigned short* Um2 = z ? P1 : P0;
    unsigned short* Un        = z ? O1 : O0;

    int tid = threadIdx.x;
    int w = tid >> 6, l = tid & 63;
    int wr = w >> 1, wc = w & 1;           // 2x2 wave grid, 64x64 each
    int r0 = blockIdx.y * 128, c0 = blockIdx.x * 128;

    // staging: per K-step each operand tile is 128 rows x 32 cols bf16 = 8192 B.
    // One GLD16 over 4 waves moves 4096 B -> 2 issues per operand.
    // Issue c covers rows c*64 + w*16 + (l>>2); stored chunk (l&3) sources
    // global chunk (l&3) ^ (((l>>2) >> 1) & 3)   [XOR key = (row mod 16)>>1 & 3]
    int srow = l >> 2;                       // row within the 16-row wave group
    int schk = ((l & 3) ^ ((l >> 3) & 3)) * 8;
    const unsigned short* ga  = A  + (size_t)(r0 + w * 16 + srow) * NN + schk;
    const unsigned short* gb  = BT + (size_t)(c0 + w * 16 + srow) * NN + schk;
    const unsigned short* ga2 = ga + (size_t)64 * NN;
    const unsigned short* gb2 = gb + (size_t)64 * NN;
    const int wo  = w * 512;                 // wave-uniform LDS offsets (elements)
    const int wo2 = 2048 + w * 512;

#define STAGE_TILE(buf, kk) do {                                                \
        GLD16(ga  + (kk), &As[buf][wo]);                                        \
        GLD16(ga2 + (kk), &As[buf][wo2]);                                       \
        GLD16(gb  + (kk), &Bs[buf][wo]);                                        \
        GLD16(gb2 + (kk), &Bs[buf][wo2]);                                       \
    } while (0)

    f32x4 acc[4][4] = {};
    int lr = l & 15, g = l >> 4;
    int rchk = (g ^ ((lr >> 1) & 3)) * 8;  // same XOR key on the read side

    STAGE_TILE(0, 0);
    int cur = 0;
    for (int k0 = 0; k0 < NN; k0 += 32) {
        __syncthreads();                    // drains vmcnt -> buf[cur] ready
        if (k0 + 32 < NN) STAGE_TILE(cur ^ 1, k0 + 32);   // prefetch next K-step
        const unsigned short* as = As[cur];
        const unsigned short* bs = Bs[cur];
        bf16x8 af[4], bf[4];
#pragma unroll
        for (int m = 0; m < 4; ++m)
            af[m] = *(const bf16x8*)(as + (wr * 64 + m * 16 + lr) * 32 + rchk);
#pragma unroll
        for (int n = 0; n < 4; ++n)
            bf[n] = *(const bf16x8*)(bs + (wc * 64 + n * 16 + lr) * 32 + rchk);
#pragma unroll
        for (int m = 0; m < 4; ++m)
#pragma unroll
            for (int n = 0; n < 4; ++n)
                acc[m][n] = __builtin_amdgcn_mfma_f32_16x16x32_bf16(af[m], bf[n], acc[m][n], 0, 0, 0);
        cur ^= 1;
    }
#undef STAGE_TILE

#pragma unroll
    for (int m = 0; m < 4; ++m)
#pragma unroll
        for (int n = 0; n < 4; ++n)
#pragma unroll
            for (int r = 0; r < 4; ++r) {
                int row = r0 + wr * 64 + m * 16 + g * 4 + r;
                int col = c0 + wc * 64 + n * 16 + lr;
                size_t off = (size_t)row * NN + col;
                float prev = first ? (row == col ? 1.f : 0.f) : bf2f(Um2[off]);
                Un[off] = f2bf(2.f * acc[m][n][r] - prev);
            }
}

// ---------------- kernel 6: fused gather + head projection ----------------
// t_1[i][j] = Lb[i][j];  t_k[i][j] = U_k[j][i] (k>=2).  f_h = b_h + sum_k w[h][k-1]*t_k
__global__ __launch_bounds__(256) void k_gather(
    const unsigned short* __restrict__ Lb,
    const unsigned short* __restrict__ U2, const unsigned short* __restrict__ U3,
    const unsigned short* __restrict__ U4, const unsigned short* __restrict__ U5,
    const unsigned short* __restrict__ U6, const unsigned short* __restrict__ U7,
    const unsigned short* __restrict__ U8,
    const float* __restrict__ w, const float* __restrict__ bias,
    float* __restrict__ fout) {
    __shared__ unsigned short G[64 * 66];
    int t = threadIdx.x;
    int I0 = blockIdx.y * 64, J0 = blockIdx.x * 64;
    int jo = t & 63, ig = t >> 6;
    int sr = t >> 2, scb = (t & 3) * 16;

    float acc[4][16];
#pragma unroll
    for (int h = 0; h < 4; ++h)
#pragma unroll
        for (int s = 0; s < 16; ++s) acc[h][s] = 0.f;

    const unsigned short* mats[8] = {Lb, U2, U3, U4, U5, U6, U7, U8};
#pragma unroll
    for (int kk = 0; kk < 8; ++kk) {
        const unsigned short* M = mats[kk];
        int R0 = (kk == 0) ? I0 : J0;
        int C0 = (kk == 0) ? J0 : I0;
        __syncthreads();
        {
            const uint4* src = (const uint4*)(M + (size_t)(R0 + sr) * NN + C0 + scb);
            uint4 v0 = src[0], v1 = src[1];
            unsigned* d = (unsigned*)&G[sr * 66 + scb];
            d[0] = v0.x; d[1] = v0.y; d[2] = v0.z; d[3] = v0.w;
            d[4] = v1.x; d[5] = v1.y; d[6] = v1.z; d[7] = v1.w;
        }
        __syncthreads();
        float c0w = w[0 * KORD + kk], c1w = w[1 * KORD + kk];
        float c2w = w[2 * KORD + kk], c3w = w[3 * KORD + kk];
#pragma unroll
        for (int s = 0; s < 16; ++s) {
            int io = ig * 16 + s;
            unsigned short raw = (kk == 0) ? G[io * 66 + jo] : G[jo * 66 + io];
            float v = bf2f(raw);
            acc[0][s] += c0w * v;
            acc[1][s] += c1w * v;
            acc[2][s] += c2w * v;
            acc[3][s] += c3w * v;
        }
    }
    float b0v = bias[0], b1v = bias[1], b2v = bias[2], b3v = bias[3];
#pragma unroll
    for (int s = 0; s < 16; ++s) {
        int i = I0 + ig * 16 + s;
        int j = J0 + jo;
        if (i == j) continue;
        size_t e = (size_t)i * NM1 + (j < i ? j : j - 1);
        fout[0 * (size_t)EDGES + e] = b0v + acc[0][s];
        fout[1 * (size_t)EDGES + e] = b1v + acc[1][s];
        fout[2 * (size_t)EDGES + e] = b2v + acc[2][s];
        fout[3 * (size_t)EDGES + e] = b3v + acc[3][s];
    }
}

extern "C" void kernel_launch(void* const* d_in, const int* in_sizes, int n_in,
                              void* d_out, int out_size, void* d_ws, size_t ws_size,
                              hipStream_t stream) {
    const float* logits = (const float*)d_in[1];
    const float* w0 = (const float*)d_in[2];
    const float* b0 = (const float*)d_in[3];
    const float* w1 = (const float*)d_in[4];
    const float* b1 = (const float*)d_in[5];
    float* out = (float*)d_out;

    char* ws = (char*)d_ws;
    const size_t MATB = (size_t)NN * NN * sizeof(unsigned short);   // 8 MiB
    unsigned short* Lb0 = (unsigned short*)(ws);
    unsigned short* Lb1 = (unsigned short*)(ws + MATB);
    unsigned short* U0[9];   // U0[2..8] branch-0 Chebyshev transposes (in ws)
    for (int k = 2; k <= 8; ++k) U0[k] = (unsigned short*)(ws + (size_t)k * MATB);
    float* dinv = (float*)(ws + 9 * MATB);              // 72 MiB offset, 16 KB
    // branch-1 scratch lives in the f-region of d_out (written later by gathers)
    unsigned short* obase = (unsigned short*)(out + 2 * (size_t)EDGES);
    unsigned short* U1[9];
    for (int k = 2; k <= 8; ++k) U1[k] = obase + (size_t)(k - 2) * NN * NN;
    unsigned short* LT0 = U0[8];   // L^T lives in the U8 slot until step 8 writes it
    unsigned short* LT1 = U1[8];

    k_prob<<<(EDGES + 255) / 256, 256, 0, stream>>>(logits, out);
    k_dinv<<<dim3(NN, 2), 256, 0, stream>>>(out, dinv);
    k_build<<<dim3((NN * NN) / 256, 2), 256, 0, stream>>>(out, dinv, Lb0, Lb1);
    k_transpose<<<dim3(32, 32, 2), 256, 0, stream>>>(Lb0, Lb1, LT0, LT1);

    for (int n = 2; n <= 8; ++n) {
        const unsigned short* A0p = (n == 2) ? LT0 : U0[n - 1];
        const unsigned short* A1p = (n == 2) ? LT1 : U1[n - 1];
        const unsigned short* P0p = (n <= 3) ? LT0 : U0[n - 2];
        const unsigned short* P1p = (n <= 3) ? LT1 : U1[n - 2];
        k_cheb<<<dim3(16, 16, 2), 256, 0, stream>>>(A0p, A1p, Lb0, Lb1, P0p, P1p,
                                                    U0[n], U1[n], (n == 2) ? 1 : 0);
    }

    // gather branch 1 FIRST (its U scratch sits inside out[2E..6E], which the
    // branch-0 gather overwrites afterwards)
    float* f1 = out + 2 * (size_t)EDGES + 4 * (size_t)EDGES;
    k_gather<<<dim3(32, 32), 256, 0, stream>>>(Lb1, U1[2], U1[3], U1[4], U1[5], U1[6], U1[7], U1[8],
                                               w1, b1, f1);
    float* f0 = out + 2 * (size_t)EDGES;
    k_gather<<<dim3(32, 32), 256, 0, stream>>>(Lb0, U0[2], U0[3], U0[4], U0[5], U0[6], U0[7], U0[8],
                                               w0, b0, f0);
}

// Round 7
// 617.089 us; speedup vs baseline: 1.1918x; 1.1918x over previous
//
#include <hip/hip_runtime.h>
#include <math.h>

#define NN 2048
#define NM1 2047
#define EDGES (NN * NM1)      // 4,192,256
#define KORD 8
#define NHEADS 4
#define BETA 0.5f
#define EPSV 1e-6f

typedef __attribute__((ext_vector_type(8))) short bf16x8;
typedef __attribute__((ext_vector_type(4))) float f32x4;

__device__ __forceinline__ unsigned short f2bf(float f) {
    unsigned u = __builtin_bit_cast(unsigned, f);
    u += 0x7FFF + ((u >> 16) & 1);          // round-to-nearest-even
    return (unsigned short)(u >> 16);
}
__device__ __forceinline__ float bf2f(unsigned short h) {
    unsigned u = ((unsigned)h) << 16;
    return __builtin_bit_cast(float, u);
}

#define GLD16(gp, lp) __builtin_amdgcn_global_load_lds(                         \
    (const __attribute__((address_space(1))) void*)(gp),                        \
    (__attribute__((address_space(3))) void*)(lp), 16, 0, 0)

// ---------------- kernel 1: edge softmax (runs LAST; writes final edge_prob) ----------------
__global__ void k_prob(const float* __restrict__ logits, float* __restrict__ out) {
    int e = blockIdx.x * 256 + threadIdx.x;
    if (e >= EDGES) return;
    float l0 = logits[e];
    float l1 = logits[EDGES + e];
    float p0 = 1.f / (1.f + __expf(BETA * (l1 - l0)));
    float p1 = 1.f / (1.f + __expf(BETA * (l0 - l1)));
    out[e]         = p0;
    out[EDGES + e] = p1;
}

// ---------------- kernel 2: row sums from logits -> dinv[2][NN] ----------------
// p0 + p1 = 1 exactly (2-way softmax) => sum1 = 2047 - sum0: one pass serves both branches.
__global__ __launch_bounds__(256) void k_dinv(const float* __restrict__ logits, float* __restrict__ dinv) {
    int row = blockIdx.x;
    const float* r0 = logits + (size_t)row * NM1;
    const float* r1 = r0 + EDGES;
    float s = 0.f;
    for (int t = threadIdx.x; t < NM1; t += 256) {
        float l0 = r0[t], l1 = r1[t];
        s += 1.f / (1.f + __expf(BETA * (l1 - l0)));
    }
    for (int off = 32; off; off >>= 1) s += __shfl_down(s, off);
    __shared__ float red[4];
    if ((threadIdx.x & 63) == 0) red[threadIdx.x >> 6] = s;
    __syncthreads();
    if (threadIdx.x == 0) {
        float s0 = red[0] + red[1] + red[2] + red[3];
        dinv[row]      = 1.f / sqrtf(s0 + EPSV);
        dinv[NN + row] = 1.f / sqrtf((float)NM1 - s0 + EPSV);
    }
}

// ---------------- kernel 3: Lb = bf16(-dinv_i * p * dinv_j), diag 0, both branches ----------------
__global__ __launch_bounds__(256) void k_build(const float* __restrict__ logits, const float* __restrict__ dinv,
                                               unsigned short* __restrict__ Lb0, unsigned short* __restrict__ Lb1) {
    int idx = blockIdx.x * 256 + threadIdx.x;   // over N*N
    int i = idx >> 11, j = idx & (NN - 1);
    float v0 = 0.f, v1 = 0.f;
    if (i != j) {
        size_t e = (size_t)i * NM1 + (j < i ? j : j - 1);
        float l0 = logits[e], l1 = logits[EDGES + e];
        float p0 = 1.f / (1.f + __expf(BETA * (l1 - l0)));
        v0 = -dinv[i] * p0 * dinv[j];
        v1 = -dinv[NN + i] * (1.f - p0) * dinv[NN + j];
    }
    Lb0[idx] = f2bf(v0);
    Lb1[idx] = f2bf(v1);
}

// ---------------- kernel 4: 64x64 bf16 transpose (dual-branch) ----------------
__global__ __launch_bounds__(256) void k_transpose(
    const unsigned short* __restrict__ S0, const unsigned short* __restrict__ S1,
    unsigned short* __restrict__ D0, unsigned short* __restrict__ D1) {
    __shared__ unsigned short T[64 * 66];
    const unsigned short* S = blockIdx.z ? S1 : S0;
    unsigned short* D = blockIdx.z ? D1 : D0;
    int t = threadIdx.x;
    int I0 = blockIdx.y * 64, J0 = blockIdx.x * 64;
    int r = t >> 2, cb = (t & 3) * 16;
    {
        const uint4* src = (const uint4*)(S + (size_t)(I0 + r) * NN + J0 + cb);
        uint4 v0 = src[0], v1 = src[1];
        unsigned* d = (unsigned*)&T[r * 66 + cb];
        d[0] = v0.x; d[1] = v0.y; d[2] = v0.z; d[3] = v0.w;
        d[4] = v1.x; d[5] = v1.y; d[6] = v1.z; d[7] = v1.w;
    }
    __syncthreads();
    union { unsigned short u[16]; uint4 q[2]; } pk;
#pragma unroll
    for (int q = 0; q < 16; ++q) pk.u[q] = T[(cb + q) * 66 + r];
    unsigned short* dst = D + (size_t)(J0 + r) * NN + I0 + cb;
    ((uint4*)dst)[0] = pk.q[0];
    ((uint4*)dst)[1] = pk.q[1];
}

// ---------------- GEMM core: Un = 2*(A @ BT^T) - (first ? I : Um2) ----------------
// 128x128 tile, 4 waves, each 64x64 via 4x4 frags of 16x16x32; XOR chunk swizzle
// both sides (rule #21). Single-phase schedule (R6 A/B: dbuf regressed 696->735).
__device__ __forceinline__ void gemm_core(
    const unsigned short* __restrict__ A, const unsigned short* __restrict__ BT,
    const unsigned short* __restrict__ Um2, unsigned short* __restrict__ Un,
    int first, int r0, int c0) {
    __shared__ unsigned short As[128 * 32];   // linear [row][k], k-chunks XOR-swizzled
    __shared__ unsigned short Bs[128 * 32];

    int tid = threadIdx.x;
    int w = tid >> 6, l = tid & 63;
    int wr = w >> 1, wc = w & 1;           // 2x2 wave grid, 64x64 each

    // staging: 128 rows x 32 cols bf16 = 8192 B per operand per K-step; 2 GLD16 each.
    // stored chunk (l&3) sources global chunk (l&3) ^ (((row mod 16)>>1)&3)
    int srow = l >> 2;
    int schk = ((l & 3) ^ ((l >> 3) & 3)) * 8;
    const unsigned short* ga  = A  + (size_t)(r0 + w * 16 + srow) * NN + schk;
    const unsigned short* gb  = BT + (size_t)(c0 + w * 16 + srow) * NN + schk;
    const unsigned short* ga2 = ga + (size_t)64 * NN;
    const unsigned short* gb2 = gb + (size_t)64 * NN;
    unsigned short* lA  = As + w * 512;            // wave-uniform bases
    unsigned short* lA2 = As + 2048 + w * 512;
    unsigned short* lB  = Bs + w * 512;
    unsigned short* lB2 = Bs + 2048 + w * 512;

    f32x4 acc[4][4] = {};
    int lr = l & 15, g = l >> 4;
    int rchk = (g ^ ((lr >> 1) & 3)) * 8;  // same XOR key on the read side

    for (int k0 = 0; k0 < NN; k0 += 32) {
        __syncthreads();
        GLD16(ga + k0, lA);
        GLD16(ga2 + k0, lA2);
        GLD16(gb + k0, lB);
        GLD16(gb2 + k0, lB2);
        __syncthreads();
        bf16x8 af[4], bf[4];
#pragma unroll
        for (int m = 0; m < 4; ++m)
            af[m] = *(const bf16x8*)(As + (wr * 64 + m * 16 + lr) * 32 + rchk);
#pragma unroll
        for (int n = 0; n < 4; ++n)
            bf[n] = *(const bf16x8*)(Bs + (wc * 64 + n * 16 + lr) * 32 + rchk);
#pragma unroll
        for (int m = 0; m < 4; ++m)
#pragma unroll
            for (int n = 0; n < 4; ++n)
                acc[m][n] = __builtin_amdgcn_mfma_f32_16x16x32_bf16(af[m], bf[n], acc[m][n], 0, 0, 0);
    }

#pragma unroll
    for (int m = 0; m < 4; ++m)
#pragma unroll
        for (int n = 0; n < 4; ++n)
#pragma unroll
            for (int r = 0; r < 4; ++r) {
                int row = r0 + wr * 64 + m * 16 + g * 4 + r;
                int col = c0 + wc * 64 + n * 16 + lr;
                size_t off = (size_t)row * NN + col;
                float prev = first ? (row == col ? 1.f : 0.f) : bf2f(Um2[off]);
                Un[off] = f2bf(2.f * acc[m][n][r] - prev);
            }
}

// GEMM1: U2 = 2*(LT @ Lb^T) - I, dual-branch, grid (16,16,2)
__global__ __launch_bounds__(256, 4) void k_cheb1(
    const unsigned short* __restrict__ LT0, const unsigned short* __restrict__ LT1,
    const unsigned short* __restrict__ Lb0, const unsigned short* __restrict__ Lb1,
    unsigned short* __restrict__ U20, unsigned short* __restrict__ U21) {
    int z = blockIdx.z;
    gemm_core(z ? LT1 : LT0, z ? Lb1 : Lb0, z ? LT1 : LT0, z ? U21 : U20, 1,
              blockIdx.y * 128, blockIdx.x * 128);
}

// Pair GEMM: two outputs per branch sharing BT = V2 (= U2^T); grid (16,32,2), 4 blocks/CU.
// half = blockIdx.y>>4 selects {lo,hi} operand set.
__global__ __launch_bounds__(256, 4) void k_chebp(
    const unsigned short* __restrict__ Alo0, const unsigned short* __restrict__ Ahi0,
    const unsigned short* __restrict__ Alo1, const unsigned short* __restrict__ Ahi1,
    const unsigned short* __restrict__ BT0,  const unsigned short* __restrict__ BT1,
    const unsigned short* __restrict__ Plo0, const unsigned short* __restrict__ Phi0,
    const unsigned short* __restrict__ Plo1, const unsigned short* __restrict__ Phi1,
    unsigned short* __restrict__ Olo0, unsigned short* __restrict__ Ohi0,
    unsigned short* __restrict__ Olo1, unsigned short* __restrict__ Ohi1,
    int firstlo, int firsthi) {
    int z = blockIdx.z;
    int half = blockIdx.y >> 4, my = blockIdx.y & 15;
    const unsigned short* A  = z ? (half ? Ahi1 : Alo1) : (half ? Ahi0 : Alo0);
    const unsigned short* BT = z ? BT1 : BT0;
    const unsigned short* P  = z ? (half ? Phi1 : Plo1) : (half ? Phi0 : Plo0);
    unsigned short* O        = z ? (half ? Ohi1 : Olo1) : (half ? Ohi0 : Olo0);
    gemm_core(A, BT, P, O, half ? firsthi : firstlo, my * 128, blockIdx.x * 128);
}

// ---------------- kernel 6: fused gather + head projection ----------------
// t_k[i][j] = U_k[j][i] for ALL k (M1 = LT = U_1).  f_h = b_h + sum_k w[h][k-1]*t_k
__global__ __launch_bounds__(256) void k_gather(
    const unsigned short* __restrict__ M1, const unsigned short* __restrict__ M2,
    const unsigned short* __restrict__ M3, const unsigned short* __restrict__ M4,
    const unsigned short* __restrict__ M5, const unsigned short* __restrict__ M6,
    const unsigned short* __restrict__ M7, const unsigned short* __restrict__ M8,
    const float* __restrict__ w, const float* __restrict__ bias,
    float* __restrict__ fout) {
    __shared__ unsigned short G[64 * 66];
    int t = threadIdx.x;
    int I0 = blockIdx.y * 64, J0 = blockIdx.x * 64;
    int jo = t & 63, ig = t >> 6;
    int sr = t >> 2, scb = (t & 3) * 16;

    float acc[4][16];
#pragma unroll
    for (int h = 0; h < 4; ++h)
#pragma unroll
        for (int s = 0; s < 16; ++s) acc[h][s] = 0.f;

    const unsigned short* mats[8] = {M1, M2, M3, M4, M5, M6, M7, M8};
#pragma unroll
    for (int kk = 0; kk < 8; ++kk) {
        const unsigned short* M = mats[kk];
        __syncthreads();
        {
            const uint4* src = (const uint4*)(M + (size_t)(J0 + sr) * NN + I0 + scb);
            uint4 v0 = src[0], v1 = src[1];
            unsigned* d = (unsigned*)&G[sr * 66 + scb];
            d[0] = v0.x; d[1] = v0.y; d[2] = v0.z; d[3] = v0.w;
            d[4] = v1.x; d[5] = v1.y; d[6] = v1.z; d[7] = v1.w;
        }
        __syncthreads();
        float c0w = w[0 * KORD + kk], c1w = w[1 * KORD + kk];
        float c2w = w[2 * KORD + kk], c3w = w[3 * KORD + kk];
#pragma unroll
        for (int s = 0; s < 16; ++s) {
            int io = ig * 16 + s;
            float v = bf2f(G[jo * 66 + io]);
            acc[0][s] += c0w * v;
            acc[1][s] += c1w * v;
            acc[2][s] += c2w * v;
            acc[3][s] += c3w * v;
        }
    }
    float b0v = bias[0], b1v = bias[1], b2v = bias[2], b3v = bias[3];
#pragma unroll
    for (int s = 0; s < 16; ++s) {
        int i = I0 + ig * 16 + s;
        int j = J0 + jo;
        if (i == j) continue;
        size_t e = (size_t)i * NM1 + (j < i ? j : j - 1);
        fout[0 * (size_t)EDGES + e] = b0v + acc[0][s];
        fout[1 * (size_t)EDGES + e] = b1v + acc[1][s];
        fout[2 * (size_t)EDGES + e] = b2v + acc[2][s];
        fout[3 * (size_t)EDGES + e] = b3v + acc[3][s];
    }
}

extern "C" void kernel_launch(void* const* d_in, const int* in_sizes, int n_in,
                              void* d_out, int out_size, void* d_ws, size_t ws_size,
                              hipStream_t stream) {
    const float* logits = (const float*)d_in[1];
    const float* w0 = (const float*)d_in[2];
    const float* b0 = (const float*)d_in[3];
    const float* w1 = (const float*)d_in[4];
    const float* b1 = (const float*)d_in[5];
    float* out = (float*)d_out;

    const size_t MATB = (size_t)NN * NN * sizeof(unsigned short);   // 8 MiB
    // branch-0 slots in ws: [0]=Lb0 (V2_0 after), [1]=LT0, [2..8]=U0[2..8]  (75.5 MiB)
    char* ws = (char*)d_ws;
    unsigned short* s0[9];
    for (int k = 0; k < 9; ++k) s0[k] = (unsigned short*)(ws + (size_t)k * MATB);
    float* dinv = (float*)(ws + 9 * MATB);
    // branch-1 slots in d_out [0, 75.5 MiB) — f1 (written by b1-gather) starts at 100.6 MiB;
    // f0 and edge_prob regions are rewritten AFTER branch-1 scratch is dead.
    char* ob = (char*)d_out;
    unsigned short* s1[9];
    for (int k = 0; k < 9; ++k) s1[k] = (unsigned short*)(ob + (size_t)k * MATB);

    k_dinv<<<NN, 256, 0, stream>>>(logits, dinv);
    k_build<<<(NN * NN) / 256, 256, 0, stream>>>(logits, dinv, s0[0], s1[0]);
    k_transpose<<<dim3(32, 32, 2), 256, 0, stream>>>(s0[0], s1[0], s0[1], s1[1]);  // Lb -> LT

    // U2 = 2*(U1 @ L^T) - I
    k_cheb1<<<dim3(16, 16, 2), 256, 0, stream>>>(s0[1], s1[1], s0[0], s1[0], s0[2], s1[2]);
    // V2 = U2^T, overwrites Lb (dead after GEMM1)
    k_transpose<<<dim3(32, 32, 2), 256, 0, stream>>>(s0[2], s1[2], s0[0], s1[0]);

    // pair1: U3 = 2*U1@U2 - U1 (A=LT,P=LT) ; U4 = 2*U2@U2 - I (A=U2, first)
    k_chebp<<<dim3(16, 32, 2), 256, 0, stream>>>(
        s0[1], s0[2], s1[1], s1[2], s0[0], s1[0],
        s0[1], s0[2], s1[1], s1[2],            // Phi = dummy (firsthi=1)
        s0[3], s0[4], s1[3], s1[4], 0, 1);
    // pair2: U5 = 2*U3@U2 - U1 ; U6 = 2*U4@U2 - U2
    k_chebp<<<dim3(16, 32, 2), 256, 0, stream>>>(
        s0[3], s0[4], s1[3], s1[4], s0[0], s1[0],
        s0[1], s0[2], s1[1], s1[2],
        s0[5], s0[6], s1[5], s1[6], 0, 0);
    // pair3: U7 = 2*U5@U2 - U3 ; U8 = 2*U6@U2 - U4
    k_chebp<<<dim3(16, 32, 2), 256, 0, stream>>>(
        s0[5], s0[6], s1[5], s1[6], s0[0], s1[0],
        s0[3], s0[4], s1[3], s1[4],
        s0[7], s0[8], s1[7], s1[8], 0, 0);

    // gathers: branch 1 first (its scratch lives below f0/edge regions written later)
    float* f1 = out + 6 * (size_t)EDGES;
    k_gather<<<dim3(32, 32), 256, 0, stream>>>(s1[1], s1[2], s1[3], s1[4], s1[5], s1[6], s1[7], s1[8],
                                               w1, b1, f1);
    float* f0 = out + 2 * (size_t)EDGES;
    k_gather<<<dim3(32, 32), 256, 0, stream>>>(s0[1], s0[2], s0[3], s0[4], s0[5], s0[6], s0[7], s0[8],
                                               w0, b0, f0);
    // edge_prob last (branch-1 scratch overlapped this region)
    k_prob<<<(EDGES + 255) / 256, 256, 0, stream>>>(logits, out);
}